// Round 1
// baseline (673.282 us; speedup 1.0000x reference)
//
#include <hip/hip_runtime.h>
#include <cstdint>
#include <cstddef>

// Problem dims (fixed)
#define CDIM 8192
#define NDIM 1024   // H*W
#define C8D  1024

typedef __bf16 bf16_t;
typedef __bf16 bf16x8 __attribute__((ext_vector_type(8)));
typedef __bf16 bf16x4 __attribute__((ext_vector_type(4)));
typedef float  f32x4  __attribute__((ext_vector_type(4)));

__device__ __forceinline__ void gload_lds16(const void* g, void* l) {
    __builtin_amdgcn_global_load_lds((const __attribute__((address_space(1))) void*)g,
                                     (__attribute__((address_space(3))) void*)l, 16, 0, 0);
}

// ---------------------------------------------------------------------------
// fp32 -> bf16 elementwise convert, 8 elems/thread, grid-stride
__global__ __launch_bounds__(256) void cvt_bf16_k(const float* __restrict__ in,
                                                  bf16_t* __restrict__ out, int n8) {
    int idx = blockIdx.x * 256 + threadIdx.x;
    int stride = gridDim.x * 256;
    for (int i = idx; i < n8; i += stride) {
        size_t off = (size_t)i * 8;
        float4 a = *(const float4*)(in + off);
        float4 b = *(const float4*)(in + off + 4);
        bf16x8 o = { (__bf16)a.x, (__bf16)a.y, (__bf16)a.z, (__bf16)a.w,
                     (__bf16)b.x, (__bf16)b.y, (__bf16)b.z, (__bf16)b.w };
        *(bf16x8*)(out + off) = o;
    }
}

// ---------------------------------------------------------------------------
// x (C=8192, N=1024) fp32 -> xT (N, C) bf16, LDS-tiled transpose
__global__ __launch_bounds__(256) void transpose_cvt_x(const float* __restrict__ x,
                                                       bf16_t* __restrict__ xT) {
    __shared__ float t[32][33];
    const int n0 = blockIdx.x * 32, c0 = blockIdx.y * 32;
    const int tx = threadIdx.x, ty = threadIdx.y; // block (32,8)
    #pragma unroll
    for (int i = 0; i < 4; ++i)
        t[ty + i * 8][tx] = x[(size_t)(c0 + ty + i * 8) * NDIM + n0 + tx];
    __syncthreads();
    #pragma unroll
    for (int i = 0; i < 4; ++i)
        xT[(size_t)(n0 + ty + i * 8) * CDIM + c0 + tx] = (__bf16)t[tx][ty + i * 8];
}

// ---------------------------------------------------------------------------
// bt-GEMM: C[i,j] = sum_k A[i,k] * B[j,k];  A (M,K) row-major, B (N,K) row-major.
// 128x128 tile, BK=32, 4 waves (2x2), mfma_f32_16x16x32_bf16, global_load_lds w16.
// EPI: 0 = v*e0[j]+e1[j] (col scale/shift)     -> qT/kT
//      1 = v*e0[i]+e1[i] (row scale/shift)     -> v
//      2 = v*(1/1023)/(e0[j]*e1[j])            -> ppmcc
//      3 = gs[0]*v + e0[i*N+j]                 -> gamma*out + x
// blockIdx.z selects the {B, C, e0, e1} pointer set (dual launch for q & k).
template <int EPI, typename OutT>
__global__ __launch_bounds__(256) void gemm_bt(
    const bf16_t* __restrict__ A,
    const bf16_t* __restrict__ B0, const bf16_t* __restrict__ B1,
    OutT* __restrict__ C0, OutT* __restrict__ C1,
    int M, int N, int K,
    const float* __restrict__ e0a, const float* __restrict__ e1a,
    const float* __restrict__ e0b, const float* __restrict__ e1b,
    const float* __restrict__ gs)
{
    const bf16_t* B = B0; OutT* C = C0;
    const float* e0 = e0a; const float* e1 = e1a;
    if (blockIdx.z) { B = B1; C = C1; e0 = e0b; e1 = e1b; }

    const int tid  = threadIdx.x;
    const int row0 = blockIdx.y * 128;
    const int col0 = blockIdx.x * 128;

    __shared__ __align__(16) bf16_t As[128 * 32];
    __shared__ __align__(16) bf16_t Bs[128 * 32];

    const int lane = tid & 63;
    const int w    = tid >> 6;
    const int wm   = (w >> 1) * 64;
    const int wn   = (w & 1) * 64;
    const int lr   = lane & 15;
    const int kg   = (lane >> 4) * 8;

    f32x4 acc[4][4];
    #pragma unroll
    for (int a_ = 0; a_ < 4; ++a_)
        #pragma unroll
        for (int b_ = 0; b_ < 4; ++b_)
            acc[a_][b_] = (f32x4){0.f, 0.f, 0.f, 0.f};

    // staging geometry: 128 rows x 32 cols bf16 = 8192B; 256 thr x 16B x 2 issues
    const int eA = tid * 8;
    const int eB = (256 + tid) * 8;
    const int rA = eA >> 5, cA = eA & 31;
    const int rB = eB >> 5, cB = eB & 31;

    for (int kb = 0; kb < K; kb += 32) {
        gload_lds16(A + (size_t)(row0 + rA) * K + kb + cA, As + eA);
        gload_lds16(A + (size_t)(row0 + rB) * K + kb + cB, As + eB);
        gload_lds16(B + (size_t)(col0 + rA) * K + kb + cA, Bs + eA);
        gload_lds16(B + (size_t)(col0 + rB) * K + kb + cB, Bs + eB);
        __syncthreads();

        bf16x8 av[4], bv[4];
        #pragma unroll
        for (int mi = 0; mi < 4; ++mi)
            av[mi] = *(const bf16x8*)(As + (wm + mi * 16 + lr) * 32 + kg);
        #pragma unroll
        for (int ni = 0; ni < 4; ++ni)
            bv[ni] = *(const bf16x8*)(Bs + (wn + ni * 16 + lr) * 32 + kg);

        #pragma unroll
        for (int mi = 0; mi < 4; ++mi)
            #pragma unroll
            for (int ni = 0; ni < 4; ++ni)
                acc[mi][ni] = __builtin_amdgcn_mfma_f32_16x16x32_bf16(
                    av[mi], bv[ni], acc[mi][ni], 0, 0, 0);
        __syncthreads();
    }

    float g = 0.f;
    if (EPI == 3) g = gs[0];
    const int cr = (lane >> 4) * 4;  // C/D: col = lane&15, row = (lane>>4)*4 + r
    #pragma unroll
    for (int mi = 0; mi < 4; ++mi) {
        #pragma unroll
        for (int ni = 0; ni < 4; ++ni) {
            const int j  = col0 + wn + ni * 16 + lr;
            const int ib = row0 + wm + mi * 16 + cr;
            float s0 = 0.f, s1 = 0.f;
            if (EPI == 0 || EPI == 2) { s0 = e0[j]; s1 = e1[j]; }
            #pragma unroll
            for (int r = 0; r < 4; ++r) {
                const int i = ib + r;
                float v = acc[mi][ni][r];
                if (EPI == 0)      v = v * s0 + s1;
                else if (EPI == 1) v = v * e0[i] + e1[i];
                else if (EPI == 2) v = v * (1.0f / 1023.0f) / (s0 * s1);
                else if (EPI == 3) v = g * v + e0[(size_t)i * N + j];
                C[(size_t)i * N + j] = (OutT)v;
            }
        }
    }
}

// ---------------------------------------------------------------------------
// Column mean/std (ddof=0) of a (rows, cols) fp32 matrix. block = 64 cols x 4
// row-groups; grid (cols/64, 1, 2) with z selecting q/k.
__global__ __launch_bounds__(256) void colstats(
    const float* __restrict__ Ma, const float* __restrict__ Mb,
    float* __restrict__ meana, float* __restrict__ stda,
    float* __restrict__ meanb, float* __restrict__ stdb,
    int rows, int cols)
{
    const float* Mx = blockIdx.z ? Mb : Ma;
    float* mean = blockIdx.z ? meanb : meana;
    float* stdv = blockIdx.z ? stdb  : stda;
    const int cl = threadIdx.x & 63;
    const int rg = threadIdx.x >> 6;
    const int c  = blockIdx.x * 64 + cl;
    float s = 0.f, s2 = 0.f;
    for (int r = rg; r < rows; r += 4) {
        float v = Mx[(size_t)r * cols + c];
        s += v; s2 += v * v;
    }
    __shared__ float ls[4][64], ls2[4][64];
    ls[rg][cl] = s; ls2[rg][cl] = s2;
    __syncthreads();
    if (rg == 0) {
        s  = ls[0][cl] + ls[1][cl] + ls[2][cl] + ls[3][cl];
        s2 = ls2[0][cl] + ls2[1][cl] + ls2[2][cl] + ls2[3][cl];
        float m   = s / rows;
        float var = fmaxf(s2 / rows - m * m, 0.0f);
        mean[c] = m;
        stdv[c] = sqrtf(var);
    }
}

// ---------------------------------------------------------------------------
// Center by column mean and convert to bf16. 4 elems/thread; z selects q/k.
__global__ __launch_bounds__(256) void center_cvt(
    const float* __restrict__ Ma, const float* __restrict__ meana, bf16_t* __restrict__ Oa,
    const float* __restrict__ Mb, const float* __restrict__ meanb, bf16_t* __restrict__ Ob,
    int cols)
{
    const float* Mx = blockIdx.z ? Mb : Ma;
    const float* mu = blockIdx.z ? meanb : meana;
    bf16_t* O = blockIdx.z ? Ob : Oa;
    const size_t i = ((size_t)blockIdx.x * 256 + threadIdx.x) * 4;
    float4 v = *(const float4*)(Mx + i);
    const int c = (int)(i & (size_t)(cols - 1));
    float4 m = *(const float4*)(mu + c);
    bf16x4 o = { (__bf16)(v.x - m.x), (__bf16)(v.y - m.y),
                 (__bf16)(v.z - m.z), (__bf16)(v.w - m.w) };
    *(bf16x4*)(O + i) = o;
}

// ---------------------------------------------------------------------------
// Row softmax of P (1024x1024 fp32) -> bf16. One block (256 thr) per row.
__global__ __launch_bounds__(256) void softmax_rows(const float* __restrict__ P,
                                                    bf16_t* __restrict__ O) {
    const int row = blockIdx.x;
    const int tid = threadIdx.x;
    const float4 v = ((const float4*)(P + (size_t)row * NDIM))[tid];
    float mx = fmaxf(fmaxf(v.x, v.y), fmaxf(v.z, v.w));
    #pragma unroll
    for (int o = 32; o; o >>= 1) mx = fmaxf(mx, __shfl_xor(mx, o));
    __shared__ float red[8];
    const int w = tid >> 6, lane = tid & 63;
    if (lane == 0) red[w] = mx;
    __syncthreads();
    mx = fmaxf(fmaxf(red[0], red[1]), fmaxf(red[2], red[3]));
    float e0 = __expf(v.x - mx), e1 = __expf(v.y - mx);
    float e2 = __expf(v.z - mx), e3 = __expf(v.w - mx);
    float s = e0 + e1 + e2 + e3;
    #pragma unroll
    for (int o = 32; o; o >>= 1) s += __shfl_xor(s, o);
    if (lane == 0) red[4 + w] = s;
    __syncthreads();
    s = red[4] + red[5] + red[6] + red[7];
    const float inv = 1.0f / s;
    bf16x4 o4 = { (__bf16)(e0 * inv), (__bf16)(e1 * inv),
                  (__bf16)(e2 * inv), (__bf16)(e3 * inv) };
    ((bf16x4*)(O + (size_t)row * NDIM))[tid] = o4;
}

// ---------------------------------------------------------------------------
extern "C" void kernel_launch(void* const* d_in, const int* in_sizes, int n_in,
                              void* d_out, int out_size, void* d_ws, size_t ws_size,
                              hipStream_t stream)
{
    const float* x       = (const float*)d_in[0];
    const float* Wq      = (const float*)d_in[1];
    const float* Wk      = (const float*)d_in[2];
    const float* Wv      = (const float*)d_in[3];
    const float* q_scale = (const float*)d_in[4];
    const float* q_shift = (const float*)d_in[5];
    const float* k_scale = (const float*)d_in[6];
    const float* k_shift = (const float*)d_in[7];
    const float* v_scale = (const float*)d_in[8];
    const float* v_shift = (const float*)d_in[9];
    const float* gamma   = (const float*)d_in[10];
    float* out = (float*)d_out;

    // workspace layout (~210 MB)
    char* w = (char*)d_ws;
    bf16_t* Wv_b = (bf16_t*)w; w += (size_t)CDIM * CDIM * 2;
    bf16_t* Wq_b = (bf16_t*)w; w += (size_t)C8D  * CDIM * 2;
    bf16_t* Wk_b = (bf16_t*)w; w += (size_t)C8D  * CDIM * 2;
    bf16_t* xT   = (bf16_t*)w; w += (size_t)NDIM * CDIM * 2;
    bf16_t* v_b  = (bf16_t*)w; w += (size_t)CDIM * NDIM * 2;
    float*  qT   = (float*) w; w += (size_t)NDIM * C8D * 4;
    float*  kT   = (float*) w; w += (size_t)NDIM * C8D * 4;
    float*  P    = (float*) w; w += (size_t)NDIM * NDIM * 4;
    bf16_t* qc   = (bf16_t*)w; w += (size_t)NDIM * C8D * 2;
    bf16_t* kc   = (bf16_t*)w; w += (size_t)NDIM * C8D * 2;
    bf16_t* A0   = (bf16_t*)w; w += (size_t)NDIM * NDIM * 2;
    float*  qmean = (float*)w; w += C8D * 4;
    float*  qstd  = (float*)w; w += C8D * 4;
    float*  kmean = (float*)w; w += C8D * 4;
    float*  kstd  = (float*)w; w += C8D * 4;

    // 1. converts
    cvt_bf16_k<<<2048, 256, 0, stream>>>(Wv, Wv_b, (int)((size_t)CDIM * CDIM / 8));
    cvt_bf16_k<<<2048, 256, 0, stream>>>(Wq, Wq_b, C8D * CDIM / 8);
    cvt_bf16_k<<<2048, 256, 0, stream>>>(Wk, Wk_b, C8D * CDIM / 8);
    transpose_cvt_x<<<dim3(NDIM / 32, CDIM / 32), dim3(32, 8), 0, stream>>>(x, xT);

    // 2. v = Wv . x  (row scale/shift, bf16 out)
    gemm_bt<1, bf16_t><<<dim3(NDIM / 128, CDIM / 128, 1), 256, 0, stream>>>(
        Wv_b, xT, xT, v_b, v_b, CDIM, NDIM, CDIM,
        v_scale, v_shift, v_scale, v_shift, nullptr);

    // 3. qT / kT = xT . W^T  (col scale/shift, fp32 out), z selects q/k
    gemm_bt<0, float><<<dim3(C8D / 128, NDIM / 128, 2), 256, 0, stream>>>(
        xT, Wq_b, Wk_b, qT, kT, NDIM, C8D, CDIM,
        q_scale, q_shift, k_scale, k_shift, nullptr);

    // 4. column stats
    colstats<<<dim3(C8D / 64, 1, 2), 256, 0, stream>>>(
        qT, kT, qmean, qstd, kmean, kstd, NDIM, C8D);

    // 5. center + bf16
    center_cvt<<<dim3(NDIM * C8D / 1024, 1, 2), 256, 0, stream>>>(
        qT, qmean, qc, kT, kmean, kc, C8D);

    // 6. P = (qc . kc^T) / 1023 / (qstd[j] * kstd[j])
    gemm_bt<2, float><<<dim3(NDIM / 128, NDIM / 128, 1), 256, 0, stream>>>(
        qc, kc, kc, P, P, NDIM, NDIM, C8D,
        qstd, kstd, qstd, kstd, nullptr);

    // 7. row softmax -> A0 (bf16)
    softmax_rows<<<NDIM, 256, 0, stream>>>(P, A0);

    // 8. out = gamma * (v . A0^T) + x
    gemm_bt<3, float><<<dim3(NDIM / 128, CDIM / 128, 1), 256, 0, stream>>>(
        v_b, A0, A0, out, out, CDIM, NDIM, NDIM,
        x, x, x, x, gamma);
}

// Round 2
// 414.936 us; speedup vs baseline: 1.6226x; 1.6226x over previous
//
#include <hip/hip_runtime.h>
#include <cstdint>
#include <cstddef>

// Problem dims (fixed)
#define CDIM 8192
#define NDIM 1024   // H*W
#define C8D  1024

typedef __bf16 bf16_t;
typedef __bf16 bf16x8 __attribute__((ext_vector_type(8)));
typedef __bf16 bf16x4 __attribute__((ext_vector_type(4)));
typedef float  f32x4  __attribute__((ext_vector_type(4)));

__device__ __forceinline__ void gload_lds16(const void* g, void* l) {
    __builtin_amdgcn_global_load_lds((const __attribute__((address_space(1))) void*)g,
                                     (__attribute__((address_space(3))) void*)l, 16, 0, 0);
}

// ---------------------------------------------------------------------------
// fp32 -> bf16 elementwise convert, 8 elems/thread, grid-stride
__global__ __launch_bounds__(256) void cvt_bf16_k(const float* __restrict__ in,
                                                  bf16_t* __restrict__ out, int n8) {
    int idx = blockIdx.x * 256 + threadIdx.x;
    int stride = gridDim.x * 256;
    for (int i = idx; i < n8; i += stride) {
        size_t off = (size_t)i * 8;
        float4 a = *(const float4*)(in + off);
        float4 b = *(const float4*)(in + off + 4);
        bf16x8 o = { (__bf16)a.x, (__bf16)a.y, (__bf16)a.z, (__bf16)a.w,
                     (__bf16)b.x, (__bf16)b.y, (__bf16)b.z, (__bf16)b.w };
        *(bf16x8*)(out + off) = o;
    }
}

// ---------------------------------------------------------------------------
// x (C=8192, N=1024) fp32 -> xT (N, C) bf16, LDS-tiled transpose
__global__ __launch_bounds__(256) void transpose_cvt_x(const float* __restrict__ x,
                                                       bf16_t* __restrict__ xT) {
    __shared__ float t[32][33];
    const int n0 = blockIdx.x * 32, c0 = blockIdx.y * 32;
    const int tx = threadIdx.x, ty = threadIdx.y; // block (32,8)
    #pragma unroll
    for (int i = 0; i < 4; ++i)
        t[ty + i * 8][tx] = x[(size_t)(c0 + ty + i * 8) * NDIM + n0 + tx];
    __syncthreads();
    #pragma unroll
    for (int i = 0; i < 4; ++i)
        xT[(size_t)(n0 + ty + i * 8) * CDIM + c0 + tx] = (__bf16)t[tx][ty + i * 8];
}

// ---------------------------------------------------------------------------
// Mega-GEMM: C[i,j] = sum_k A[i,k]*B[j,k] with A = [Wv;Wq;Wk] stacked (M=10240),
// B = xT (1024 x 8192). 128x128 tile, BK=32, 4 waves, XCD-swizzled grid.
// Rows [0,8192): v-path, out bf16 with row scale/shift.
// Rows [8192,9216): q-path, out fp32 q_on (channel-major) with row scale/shift.
// Rows [9216,10240): k-path, out fp32 k_on.
__global__ __launch_bounds__(256) void mega_gemm(
    const bf16_t* __restrict__ Wv, const bf16_t* __restrict__ Wq,
    const bf16_t* __restrict__ Wk, const bf16_t* __restrict__ Bx,
    bf16_t* __restrict__ v_out, float* __restrict__ q_out, float* __restrict__ k_out,
    const float* __restrict__ v_scale, const float* __restrict__ v_shift,
    const float* __restrict__ q_scale, const float* __restrict__ q_shift,
    const float* __restrict__ k_scale, const float* __restrict__ k_shift)
{
    // XCD-aware bijective swizzle (nwg = 640, %8 == 0)
    const int gx = gridDim.x;
    const int nwg = gx * gridDim.y;
    const int lin = blockIdx.y * gx + blockIdx.x;
    const int tile = (lin & 7) * (nwg >> 3) + (lin >> 3);
    const int row0 = (tile / gx) * 128;
    const int col0 = (tile % gx) * 128;

    const bf16_t* A; const float* s0; const float* s1;
    int arow; int path; // 0=v,1=q,2=k
    if (row0 < 8192)      { A = Wv; arow = row0;        s0 = v_scale; s1 = v_shift; path = 0; }
    else if (row0 < 9216) { A = Wq; arow = row0 - 8192; s0 = q_scale; s1 = q_shift; path = 1; }
    else                  { A = Wk; arow = row0 - 9216; s0 = k_scale; s1 = k_shift; path = 2; }

    const int tid = threadIdx.x;
    __shared__ __align__(16) bf16_t As[128 * 32];
    __shared__ __align__(16) bf16_t Bs[128 * 32];

    const int lane = tid & 63;
    const int w    = tid >> 6;
    const int wm   = (w >> 1) * 64;
    const int wn   = (w & 1) * 64;
    const int lr   = lane & 15;
    const int kg   = (lane >> 4) * 8;

    f32x4 acc[4][4];
    #pragma unroll
    for (int a_ = 0; a_ < 4; ++a_)
        #pragma unroll
        for (int b_ = 0; b_ < 4; ++b_)
            acc[a_][b_] = (f32x4){0.f, 0.f, 0.f, 0.f};

    const int eA = tid * 8;
    const int eB = (256 + tid) * 8;
    const int rA = eA >> 5, cA = eA & 31;
    const int rB = eB >> 5, cB = eB & 31;

    for (int kb = 0; kb < CDIM; kb += 32) {
        gload_lds16(A + (size_t)(arow + rA) * CDIM + kb + cA, As + eA);
        gload_lds16(A + (size_t)(arow + rB) * CDIM + kb + cB, As + eB);
        gload_lds16(Bx + (size_t)(col0 + rA) * CDIM + kb + cA, Bs + eA);
        gload_lds16(Bx + (size_t)(col0 + rB) * CDIM + kb + cB, Bs + eB);
        __syncthreads();

        bf16x8 av[4], bv[4];
        #pragma unroll
        for (int mi = 0; mi < 4; ++mi)
            av[mi] = *(const bf16x8*)(As + (wm + mi * 16 + lr) * 32 + kg);
        #pragma unroll
        for (int ni = 0; ni < 4; ++ni)
            bv[ni] = *(const bf16x8*)(Bs + (wn + ni * 16 + lr) * 32 + kg);

        #pragma unroll
        for (int mi = 0; mi < 4; ++mi)
            #pragma unroll
            for (int ni = 0; ni < 4; ++ni)
                acc[mi][ni] = __builtin_amdgcn_mfma_f32_16x16x32_bf16(
                    av[mi], bv[ni], acc[mi][ni], 0, 0, 0);
        __syncthreads();
    }

    const int cr = (lane >> 4) * 4;  // C/D: col = lane&15, row = (lane>>4)*4 + r
    #pragma unroll
    for (int mi = 0; mi < 4; ++mi) {
        #pragma unroll
        for (int ni = 0; ni < 4; ++ni) {
            const int j = col0 + wn + ni * 16 + lr;
            #pragma unroll
            for (int r = 0; r < 4; ++r) {
                const int il = arow + wm + mi * 16 + cr + r; // local row in its matrix
                float v = acc[mi][ni][r] * s0[il] + s1[il];
                if (path == 0)      v_out[(size_t)il * NDIM + j] = (__bf16)v;
                else if (path == 1) q_out[(size_t)il * NDIM + j] = v;
                else                k_out[(size_t)il * NDIM + j] = v;
            }
        }
    }
}

// ---------------------------------------------------------------------------
// bt-GEMM: C[i,j] = sum_k A[i,k] * B[j,k]. XCD-swizzled.
// EPI: 2 = v*(1/1023)/(e0[j]*e1[j])  -> ppmcc
//      3 = gs[0]*v + e0[i*N+j]       -> gamma*out + x
template <int EPI, typename OutT>
__global__ __launch_bounds__(256) void gemm_bt(
    const bf16_t* __restrict__ A, const bf16_t* __restrict__ B,
    OutT* __restrict__ C, int M, int N, int K,
    const float* __restrict__ e0, const float* __restrict__ e1,
    const float* __restrict__ gs)
{
    const int gx = gridDim.x;
    const int nwg = gx * gridDim.y;
    const int lin = blockIdx.y * gx + blockIdx.x;
    int tile = lin;
    if ((nwg & 7) == 0) tile = (lin & 7) * (nwg >> 3) + (lin >> 3);
    const int row0 = (tile / gx) * 128;
    const int col0 = (tile % gx) * 128;

    const int tid = threadIdx.x;
    __shared__ __align__(16) bf16_t As[128 * 32];
    __shared__ __align__(16) bf16_t Bs[128 * 32];

    const int lane = tid & 63;
    const int w    = tid >> 6;
    const int wm   = (w >> 1) * 64;
    const int wn   = (w & 1) * 64;
    const int lr   = lane & 15;
    const int kg   = (lane >> 4) * 8;

    f32x4 acc[4][4];
    #pragma unroll
    for (int a_ = 0; a_ < 4; ++a_)
        #pragma unroll
        for (int b_ = 0; b_ < 4; ++b_)
            acc[a_][b_] = (f32x4){0.f, 0.f, 0.f, 0.f};

    const int eA = tid * 8;
    const int eB = (256 + tid) * 8;
    const int rA = eA >> 5, cA = eA & 31;
    const int rB = eB >> 5, cB = eB & 31;

    for (int kb = 0; kb < K; kb += 32) {
        gload_lds16(A + (size_t)(row0 + rA) * K + kb + cA, As + eA);
        gload_lds16(A + (size_t)(row0 + rB) * K + kb + cB, As + eB);
        gload_lds16(B + (size_t)(col0 + rA) * K + kb + cA, Bs + eA);
        gload_lds16(B + (size_t)(col0 + rB) * K + kb + cB, Bs + eB);
        __syncthreads();

        bf16x8 av[4], bv[4];
        #pragma unroll
        for (int mi = 0; mi < 4; ++mi)
            av[mi] = *(const bf16x8*)(As + (wm + mi * 16 + lr) * 32 + kg);
        #pragma unroll
        for (int ni = 0; ni < 4; ++ni)
            bv[ni] = *(const bf16x8*)(Bs + (wn + ni * 16 + lr) * 32 + kg);

        #pragma unroll
        for (int mi = 0; mi < 4; ++mi)
            #pragma unroll
            for (int ni = 0; ni < 4; ++ni)
                acc[mi][ni] = __builtin_amdgcn_mfma_f32_16x16x32_bf16(
                    av[mi], bv[ni], acc[mi][ni], 0, 0, 0);
        __syncthreads();
    }

    float g = 0.f;
    if (EPI == 3) g = gs[0];
    const int cr = (lane >> 4) * 4;
    #pragma unroll
    for (int mi = 0; mi < 4; ++mi) {
        #pragma unroll
        for (int ni = 0; ni < 4; ++ni) {
            const int j = col0 + wn + ni * 16 + lr;
            float s0 = 0.f, s1 = 0.f;
            if (EPI == 2) { s0 = e0[j]; s1 = e1[j]; }
            #pragma unroll
            for (int r = 0; r < 4; ++r) {
                const int i = row0 + wm + mi * 16 + cr + r;
                float v = acc[mi][ni][r];
                if (EPI == 2)      v = v * (1.0f / 1023.0f) / (s0 * s1);
                else if (EPI == 3) v = g * v + e0[(size_t)i * N + j];
                C[(size_t)i * N + j] = (OutT)v;
            }
        }
    }
}

// ---------------------------------------------------------------------------
// Row mean/std (ddof=0) of q_on / k_on (each 1024 x 1024 fp32). One wave/row.
__global__ __launch_bounds__(256) void rowstats(
    const float* __restrict__ Q, const float* __restrict__ Km,
    float* __restrict__ qmean, float* __restrict__ qstd,
    float* __restrict__ kmean, float* __restrict__ kstd)
{
    const int wid  = blockIdx.x * 4 + (threadIdx.x >> 6);
    const int lane = threadIdx.x & 63;
    const float* src = (wid < 1024) ? (Q + (size_t)wid * NDIM)
                                    : (Km + (size_t)(wid - 1024) * NDIM);
    float s = 0.f, s2 = 0.f;
    #pragma unroll
    for (int p = 0; p < 4; ++p) {
        float4 v = *(const float4*)(src + p * 256 + lane * 4);
        s  += v.x + v.y + v.z + v.w;
        s2 += v.x * v.x + v.y * v.y + v.z * v.z + v.w * v.w;
    }
    #pragma unroll
    for (int o = 32; o; o >>= 1) { s += __shfl_xor(s, o); s2 += __shfl_xor(s2, o); }
    if (lane == 0) {
        float m   = s / 1024.f;
        float var = fmaxf(s2 / 1024.f - m * m, 0.f);
        if (wid < 1024) { qmean[wid] = m; qstd[wid] = sqrtf(var); }
        else            { kmean[wid - 1024] = m; kstd[wid - 1024] = sqrtf(var); }
    }
}

// ---------------------------------------------------------------------------
// Center by row mean, transpose (o,n)->(n,o), convert bf16. z selects q/k.
__global__ __launch_bounds__(256) void center_tr(
    const float* __restrict__ Q, const float* __restrict__ qmu, bf16_t* __restrict__ qc,
    const float* __restrict__ Km, const float* __restrict__ kmu, bf16_t* __restrict__ kc)
{
    __shared__ float t[32][33];
    const float* M  = blockIdx.z ? Km  : Q;
    const float* mu = blockIdx.z ? kmu : qmu;
    bf16_t* O       = blockIdx.z ? kc  : qc;
    const int o0 = blockIdx.y * 32, n0 = blockIdx.x * 32;
    const int tx = threadIdx.x, ty = threadIdx.y; // block (32,8)
    #pragma unroll
    for (int i = 0; i < 4; ++i) {
        const int o = o0 + ty + i * 8;
        t[ty + i * 8][tx] = M[(size_t)o * NDIM + n0 + tx] - mu[o];
    }
    __syncthreads();
    #pragma unroll
    for (int i = 0; i < 4; ++i)
        O[(size_t)(n0 + ty + i * 8) * C8D + o0 + tx] = (__bf16)t[tx][ty + i * 8];
}

// ---------------------------------------------------------------------------
// Row softmax of P (1024x1024 fp32) -> bf16. One block (256 thr) per row.
__global__ __launch_bounds__(256) void softmax_rows(const float* __restrict__ P,
                                                    bf16_t* __restrict__ O) {
    const int row = blockIdx.x;
    const int tid = threadIdx.x;
    const float4 v = ((const float4*)(P + (size_t)row * NDIM))[tid];
    float mx = fmaxf(fmaxf(v.x, v.y), fmaxf(v.z, v.w));
    #pragma unroll
    for (int o = 32; o; o >>= 1) mx = fmaxf(mx, __shfl_xor(mx, o));
    __shared__ float red[8];
    const int w = tid >> 6, lane = tid & 63;
    if (lane == 0) red[w] = mx;
    __syncthreads();
    mx = fmaxf(fmaxf(red[0], red[1]), fmaxf(red[2], red[3]));
    float e0 = __expf(v.x - mx), e1 = __expf(v.y - mx);
    float e2 = __expf(v.z - mx), e3 = __expf(v.w - mx);
    float s = e0 + e1 + e2 + e3;
    #pragma unroll
    for (int o = 32; o; o >>= 1) s += __shfl_xor(s, o);
    if (lane == 0) red[4 + w] = s;
    __syncthreads();
    s = red[4] + red[5] + red[6] + red[7];
    const float inv = 1.0f / s;
    bf16x4 o4 = { (__bf16)(e0 * inv), (__bf16)(e1 * inv),
                  (__bf16)(e2 * inv), (__bf16)(e3 * inv) };
    ((bf16x4*)(O + (size_t)row * NDIM))[tid] = o4;
}

// ---------------------------------------------------------------------------
extern "C" void kernel_launch(void* const* d_in, const int* in_sizes, int n_in,
                              void* d_out, int out_size, void* d_ws, size_t ws_size,
                              hipStream_t stream)
{
    const float* x       = (const float*)d_in[0];
    const float* Wq      = (const float*)d_in[1];
    const float* Wk      = (const float*)d_in[2];
    const float* Wv      = (const float*)d_in[3];
    const float* q_scale = (const float*)d_in[4];
    const float* q_shift = (const float*)d_in[5];
    const float* k_scale = (const float*)d_in[6];
    const float* k_shift = (const float*)d_in[7];
    const float* v_scale = (const float*)d_in[8];
    const float* v_shift = (const float*)d_in[9];
    const float* gamma   = (const float*)d_in[10];
    float* out = (float*)d_out;

    // workspace layout (~216 MB)
    char* w = (char*)d_ws;
    bf16_t* Wv_b = (bf16_t*)w; w += (size_t)CDIM * CDIM * 2;
    bf16_t* Wq_b = (bf16_t*)w; w += (size_t)C8D  * CDIM * 2;
    bf16_t* Wk_b = (bf16_t*)w; w += (size_t)C8D  * CDIM * 2;
    bf16_t* xT   = (bf16_t*)w; w += (size_t)NDIM * CDIM * 2;
    bf16_t* v_b  = (bf16_t*)w; w += (size_t)CDIM * NDIM * 2;
    float*  q_on = (float*) w; w += (size_t)C8D * NDIM * 4;
    float*  k_on = (float*) w; w += (size_t)C8D * NDIM * 4;
    float*  P    = (float*) w; w += (size_t)NDIM * NDIM * 4;
    bf16_t* qc   = (bf16_t*)w; w += (size_t)NDIM * C8D * 2;
    bf16_t* kc   = (bf16_t*)w; w += (size_t)NDIM * C8D * 2;
    bf16_t* A0   = (bf16_t*)w; w += (size_t)NDIM * NDIM * 2;
    float*  qmean = (float*)w; w += C8D * 4;
    float*  qstd  = (float*)w; w += C8D * 4;
    float*  kmean = (float*)w; w += C8D * 4;
    float*  kstd  = (float*)w; w += C8D * 4;

    // 1. converts
    cvt_bf16_k<<<2048, 256, 0, stream>>>(Wv, Wv_b, (int)((size_t)CDIM * CDIM / 8));
    cvt_bf16_k<<<2048, 256, 0, stream>>>(Wq, Wq_b, C8D * CDIM / 8);
    cvt_bf16_k<<<2048, 256, 0, stream>>>(Wk, Wk_b, C8D * CDIM / 8);
    transpose_cvt_x<<<dim3(NDIM / 32, CDIM / 32), dim3(32, 8), 0, stream>>>(x, xT);

    // 2. mega-GEMM: [v; q_on; k_on] = [Wv;Wq;Wk] . xT^T  (640 blocks, packed)
    mega_gemm<<<dim3(NDIM / 128, 10240 / 128), 256, 0, stream>>>(
        Wv_b, Wq_b, Wk_b, xT, v_b, q_on, k_on,
        v_scale, v_shift, q_scale, q_shift, k_scale, k_shift);

    // 3. row stats of q_on / k_on (2048 waves)
    rowstats<<<512, 256, 0, stream>>>(q_on, k_on, qmean, qstd, kmean, kstd);

    // 4. center + transpose + bf16
    center_tr<<<dim3(32, 32, 2), dim3(32, 8), 0, stream>>>(
        q_on, qmean, qc, k_on, kmean, kc);

    // 5. P = (qc . kc^T) / 1023 / (qstd[j] * kstd[j])
    gemm_bt<2, float><<<dim3(NDIM / 128, NDIM / 128), 256, 0, stream>>>(
        qc, kc, P, NDIM, NDIM, C8D, qstd, kstd, nullptr);

    // 6. row softmax -> A0 (bf16)
    softmax_rows<<<NDIM, 256, 0, stream>>>(P, A0);

    // 7. out = gamma * (v . A0^T) + x
    gemm_bt<3, float><<<dim3(NDIM / 128, CDIM / 128), 256, 0, stream>>>(
        v_b, A0, out, CDIM, NDIM, NDIM, x, x, gamma);
}